// Round 7
// baseline (14586.847 us; speedup 1.0000x reference)
//
#include <hip/hip_runtime.h>
#include <hip/hip_fp16.h>

// LSTM: B=32, T=4096, D=256, H=256, gates=1024 (i,g,f,o), HORIZON=24
// Pipeline: prep_x (f32->bf16) ; prep_w (WxT bf16 ; WhA f16 rows srow=j*4+gate) ;
//           xproj MFMA GEMM -> G f16 [b][t][j][gate] (bias + forget+1 folded) ;
//           scan: 32 blocks (1 batch/CU) x 512 thr (8 waves). Recurrent matvec on the
//             MFMA pipe: gates = WhA @ h via mfma_f32_16x16x32_f16 with h REPLICATED
//             across all 16 B-columns (B-frag = one 4-addr LDS b128 per ktile; C rows
//             land in every column-lane). Rows srow=j*4+gate => lane (q,mt) holds all
//             4 gates of j=w*32+mt*4+q in acc[mt][0..3]: h computed in-register,
//             no gates roundtrip, ONE barrier/step. A-frags (256 regs) live in AGPRs
//             (MFMA reads AGPR natively - free, unlike fdot2). Epilogue de-replicated:
//             lane l16 processes mt=l16&7 via cndmask select tree.
//           head: two tiny FCs.

#define T_STEPS 4096
#define BATCH 32

typedef short short8 __attribute__((ext_vector_type(8)));
typedef _Float16 half8 __attribute__((ext_vector_type(8)));
typedef float f32x4 __attribute__((ext_vector_type(4)));
typedef _Float16 half2_t __attribute__((ext_vector_type(2)));

__device__ inline unsigned short f32_to_bf16(float f) {
  unsigned int u = __builtin_bit_cast(unsigned int, f);
  u = u + 0x7fffu + ((u >> 16) & 1u);   // RNE
  return (unsigned short)(u >> 16);
}

// ---------------- prep: x f32 -> bf16 ----------------
__global__ void k_prep_x(const float4* __restrict__ x, unsigned short* __restrict__ xbf, int n4) {
  int i = blockIdx.x * blockDim.x + threadIdx.x;
  if (i >= n4) return;
  float4 v = x[i];
  ushort4 o;
  o.x = f32_to_bf16(v.x); o.y = f32_to_bf16(v.y);
  o.z = f32_to_bf16(v.z); o.w = f32_to_bf16(v.w);
  ((ushort4*)xbf)[i] = o;
}

// ---------------- prep: weights ----------------
// WxT[n][k] = bf16(W_lstm[k][n]) for k<256 (xproj B-frags contiguous)
// WhA[srow][k] = f16(W_lstm[256+k][gate*256+j])  with srow = j*4+gate  (scan A rows)
__global__ void k_prep_w(const float* __restrict__ W, unsigned short* __restrict__ WxT,
                         _Float16* __restrict__ WhA) {
  int i = blockIdx.x * blockDim.x + threadIdx.x;
  if (i < 256 * 1024) {
    int n = i >> 8, k = i & 255;
    WxT[i] = f32_to_bf16(W[k * 1024 + n]);
  } else {
    int j = i - 256 * 1024;          // [0, 262144)
    int srow = j >> 8, k = j & 255;
    int jj = srow >> 2, gate = srow & 3;
    WhA[j] = (_Float16)W[(256 + k) * 1024 + gate * 256 + jj];
  }
}

// ---------------- xproj: gates_x = x @ Wx + b (+1 on f-gate) ----------------
// M=131072, N=1024, K=256. Output layout: G[m][j][gate] f16 (m = b*4096+t).
__global__ __launch_bounds__(256) void k_xproj(const unsigned short* __restrict__ A,
                                               const unsigned short* __restrict__ BT,
                                               const float* __restrict__ bias,
                                               __half* __restrict__ G) {
  int bm = blockIdx.x * 64;
  int bn = blockIdx.y * 64;
  int lane = threadIdx.x & 63, wave = threadIdx.x >> 6;
  int wm = (wave & 1) * 32, wn = (wave >> 1) * 32;
  int q = lane >> 4, l16 = lane & 15;

  f32x4 acc[2][2] = {};
  const unsigned short* Ab = A + (size_t)(bm + wm + l16) * 256 + q * 8;
  const unsigned short* Bb = BT + (size_t)(bn + wn + l16) * 256 + q * 8;

#pragma unroll
  for (int kk = 0; kk < 8; ++kk) {
    short8 a0 = *(const short8*)(Ab + kk * 32);
    short8 a1 = *(const short8*)(Ab + 16 * 256 + kk * 32);
    short8 b0 = *(const short8*)(Bb + kk * 32);
    short8 b1 = *(const short8*)(Bb + 16 * 256 + kk * 32);
    acc[0][0] = __builtin_amdgcn_mfma_f32_16x16x32_bf16(a0, b0, acc[0][0], 0, 0, 0);
    acc[0][1] = __builtin_amdgcn_mfma_f32_16x16x32_bf16(a0, b1, acc[0][1], 0, 0, 0);
    acc[1][0] = __builtin_amdgcn_mfma_f32_16x16x32_bf16(a1, b0, acc[1][0], 0, 0, 0);
    acc[1][1] = __builtin_amdgcn_mfma_f32_16x16x32_bf16(a1, b1, acc[1][1], 0, 0, 0);
  }

#pragma unroll
  for (int nt = 0; nt < 2; ++nt) {
    int col = bn + wn + nt * 16 + l16;
    float bv = bias[col] + ((col >= 512 && col < 768) ? 1.0f : 0.0f);
    int gate = col >> 8, jj = col & 255;
#pragma unroll
    for (int mt = 0; mt < 2; ++mt) {
#pragma unroll
      for (int r = 0; r < 4; ++r) {
        int row = bm + wm + mt * 16 + q * 4 + r;
        G[(size_t)row * 1024 + jj * 4 + gate] = __float2half_rn(acc[mt][nt][r] + bv);
      }
    }
  }
}

// ---------------- recurrent scan (MFMA within-CU) ----------------
// Wave w owns srows [w*128, w*128+128) = 8 Mtiles. Lane (q=lane>>4, l16=lane&15).
// A-frag: Af[mt][kt] = WhA[w*128+mt*16+l16][kt*32+q*8 .. +8]   (256 regs -> AGPR)
// B-frag: h replicated over columns: all l16 read the SAME b128 at kt*64+q*16 bytes.
// C: acc[mt][r] = gate row w*128+mt*16+q*4+r, identical across l16
//    => j = w*32+mt*4+q, gate = r. Lane l16 finishes mt = l16&7 (select tree).
__global__ __launch_bounds__(512, 2) void k_scan(const _Float16* __restrict__ WhA,
                                                 const __half* __restrict__ G,
                                                 float* __restrict__ hfin) {
  __shared__ __align__(16) _Float16 h2[2][256];   // double-buffered h

  const int tid = threadIdx.x;
  const int lane = tid & 63;
  const int w = tid >> 6;        // wave 0..7
  const int l16 = lane & 15;
  const int q = lane >> 4;       // 0..3
  const int b = blockIdx.x;

  // ---- load A fragments (one-time, 64 x b128 global) ----
  half8 Af[8][8];
  {
    const _Float16* ab = WhA + (size_t)(w * 128 + l16) * 256 + q * 8;
#pragma unroll
    for (int mt = 0; mt < 8; ++mt)
#pragma unroll
      for (int kt = 0; kt < 8; ++kt)
        Af[mt][kt] = *(const half8*)(ab + mt * 16 * 256 + kt * 32);
  }

  const int msel = l16 & 7;                 // mt this lane finishes
  const int j = w * 32 + msel * 4 + q;      // its hidden unit
  float cst = 0.0f;                         // c-state for j

  if (tid < 256) h2[0][tid] = (_Float16)0.0f;   // h0 = 0
  __syncthreads();

  const unsigned short* gxp = (const unsigned short*)G + (size_t)b * T_STEPS * 1024;

  for (int s = 0; s < T_STEPS; ++s) {
    // gates_x for this lane's j (8B, L2-hot; consumed after MFMA)
    uint2 gx = *(const uint2*)(gxp + ((size_t)s * 256 + j) * 4);

    // ---- B-frags: 8 reads, 4 distinct addrs/wave (broadcast within l16 groups) ----
    const _Float16* hb = h2[s & 1];
    half8 Bf[8];
#pragma unroll
    for (int kt = 0; kt < 8; ++kt)
      Bf[kt] = *(const half8*)(hb + kt * 32 + q * 8);

    // ---- 64 MFMA: acc[mt] over 8 ktiles (first ktile takes C=0: no re-zeroing) ----
    f32x4 acc[8];
#pragma unroll
    for (int mt = 0; mt < 8; ++mt)
      acc[mt] = __builtin_amdgcn_mfma_f32_16x16x32_f16(Af[mt][0], Bf[0],
                                                       f32x4{0.f, 0.f, 0.f, 0.f}, 0, 0, 0);
#pragma unroll
    for (int kt = 1; kt < 8; ++kt)
#pragma unroll
      for (int mt = 0; mt < 8; ++mt)
        acc[mt] = __builtin_amdgcn_mfma_f32_16x16x32_f16(Af[mt][kt], Bf[kt], acc[mt], 0, 0, 0);

    // ---- select this lane's mt (static unroll -> cndmask tree, no scratch) ----
    f32x4 g4 = acc[0];
#pragma unroll
    for (int m = 1; m < 8; ++m)
      if (msel == m) g4 = acc[m];

    // ---- epilogue: one j per lane ----
    half2_t g01 = __builtin_bit_cast(half2_t, gx.x);
    half2_t g23 = __builtin_bit_cast(half2_t, gx.y);
    float gi = g4[0] + (float)g01.x;
    float gg = g4[1] + (float)g01.y;
    float gf = g4[2] + (float)g23.x;   // +1 folded in xproj
    float go = g4[3] + (float)g23.y;
    float si = 1.0f / (1.0f + __expf(-gi));
    float sf = 1.0f / (1.0f + __expf(-gf));
    float so = 1.0f / (1.0f + __expf(-go));
    float eg = __expf(2.0f * gg);
    float tg = 1.0f - 2.0f / (eg + 1.0f);      // tanh, overflow-safe
    cst = sf * cst + si * tg;
    float ec = __expf(2.0f * cst);
    float tc = 1.0f - 2.0f / (ec + 1.0f);
    float h = so * tc;

    if (l16 < 8) {
      h2[(s + 1) & 1][j] = (_Float16)h;        // 32 lanes, distinct j, 2-way banks (free)
      if (s == T_STEPS - 1) hfin[b * 256 + j] = h;
    }
    __syncthreads();                           // ONE barrier per step
  }
}

// ---------------- head: out = (h@Wfc+bfc)@Wout+bout ----------------
__global__ void k_head(const float* __restrict__ hfin, const float* __restrict__ Wfc,
                       const float* __restrict__ bfc, const float* __restrict__ Wout,
                       const float* __restrict__ bout, float* __restrict__ out) {
  __shared__ float hs[256];
  __shared__ float fcs[256];
  int b = blockIdx.x, j = threadIdx.x;
  hs[j] = hfin[b * 256 + j];
  __syncthreads();
  float acc = bfc[j];
#pragma unroll 8
  for (int k = 0; k < 256; ++k) acc += hs[k] * Wfc[k * 256 + j];
  fcs[j] = acc;
  __syncthreads();
  if (j < 24) {
    float a2 = bout[j];
#pragma unroll 8
    for (int k = 0; k < 256; ++k) a2 += fcs[k] * Wout[k * 24 + j];
    out[b * 24 + j] = a2;
  }
}

extern "C" void kernel_launch(void* const* d_in, const int* in_sizes, int n_in,
                              void* d_out, int out_size, void* d_ws, size_t ws_size,
                              hipStream_t stream) {
  const float* x    = (const float*)d_in[0];
  const float* Wl   = (const float*)d_in[1];
  const float* bl   = (const float*)d_in[2];
  const float* Wfc  = (const float*)d_in[3];
  const float* bfc  = (const float*)d_in[4];
  const float* Wout = (const float*)d_in[5];
  const float* bout = (const float*)d_in[6];
  float* out = (float*)d_out;

  char* ws = (char*)d_ws;
  // ws layout (bytes), total ~321 MB
  unsigned short* xbf = (unsigned short*)ws;                    //  67108864  x as bf16
  unsigned short* WxT = (unsigned short*)(ws + 67108864);       //    524288  Wx^T bf16 [1024][256]
  _Float16*       WhA = (_Float16*)(ws + 67633152);             //    524288  Wh f16 [1024 srow][256]
  __half*         G   = (__half*)(ws + 68157440);               // 268435456  gates_x f16 [m][j][gate]
  float*          hfin= (float*)(ws + 336592896);               //     32768  final h f32

  k_prep_x<<<32768, 256, 0, stream>>>((const float4*)x, xbf, 8388608);
  k_prep_w<<<2048, 256, 0, stream>>>(Wl, WxT, WhA);
  dim3 gx(2048, 16, 1);
  k_xproj<<<gx, 256, 0, stream>>>(xbf, WxT, bl, G);
  k_scan<<<32, 512, 0, stream>>>(WhA, G, hfin);
  k_head<<<32, 256, 0, stream>>>(hfin, Wfc, bfc, Wout, bout, out);
}

// Round 8
// 7210.104 us; speedup vs baseline: 2.0231x; 2.0231x over previous
//
#include <hip/hip_runtime.h>
#include <hip/hip_fp16.h>

// LSTM: B=32, T=4096, D=256, H=256, gates=1024 (i,g,f,o), HORIZON=24
// r8 = r3's dot engine + restructured step skeleton:
//   - gate-local pairing: thread 2j owns (i_j,g_j), thread 2j+1 owns (f_j,o_j);
//     a=si*tanh(g) crosses lanes via shfl_xor(1) (DPP) -> NO gates LDS roundtrip,
//     NO second barrier, epilogue distributed over all waves.
//   - ONE raw barrier/step (lgkmcnt only) -> G-prefetch stays in flight (no vmcnt drain).
//   - h double-buffered by step parity (race-free with single barrier).
//   - G layout [m][j][gate] so each thread reads its 2 gates as one b32.
// Weights: 114 pairs resident + 14 pairs LDS quads [i][tid] (r3 winner config).

#define T_STEPS 4096
#define BATCH 32
#define RPAIRS 114
#define LQUADS 7     // pairs 114..127 in LDS

typedef short short8 __attribute__((ext_vector_type(8)));
typedef float f32x4 __attribute__((ext_vector_type(4)));
typedef _Float16 half2_t __attribute__((ext_vector_type(2)));

__device__ inline unsigned short f32_to_bf16(float f) {
  unsigned int u = __builtin_bit_cast(unsigned int, f);
  u = u + 0x7fffu + ((u >> 16) & 1u);   // RNE
  return (unsigned short)(u >> 16);
}

__device__ inline float fdot2f(unsigned int w, unsigned int h, float acc) {
#if __has_builtin(__builtin_amdgcn_fdot2)
  return __builtin_amdgcn_fdot2(__builtin_bit_cast(half2_t, w),
                                __builtin_bit_cast(half2_t, h), acc, false);
#else
  half2_t a = __builtin_bit_cast(half2_t, w);
  half2_t b = __builtin_bit_cast(half2_t, h);
  acc += (float)a.x * (float)b.x;
  acc += (float)a.y * (float)b.y;
  return acc;
#endif
}

// ---------------- prep: x f32 -> bf16 ----------------
__global__ void k_prep_x(const float4* __restrict__ x, unsigned short* __restrict__ xbf, int n4) {
  int i = blockIdx.x * blockDim.x + threadIdx.x;
  if (i >= n4) return;
  float4 v = x[i];
  ushort4 o;
  o.x = f32_to_bf16(v.x); o.y = f32_to_bf16(v.y);
  o.z = f32_to_bf16(v.z); o.w = f32_to_bf16(v.w);
  ((ushort4*)xbf)[i] = o;
}

// ---------------- prep: weights ----------------
// WxT[n][k] = bf16(W_lstm[k][n]) for k<256 (xproj B-frags contiguous)
// Whp2[p][t] = uint2{ packA, packB } for scan thread t:
//   t=2j:   colA=j (i), colB=256+j (g) ; t=2j+1: colA=512+j (f), colB=768+j (o)
//   pack(col) = f16(W[256+2p][col]) | f16(W[257+2p][col])<<16
__global__ void k_prep_w(const float* __restrict__ W, unsigned short* __restrict__ WxT,
                         uint2* __restrict__ Whp2) {
  int i = blockIdx.x * blockDim.x + threadIdx.x;
  if (i < 256 * 1024) {
    int n = i >> 8, k = i & 255;
    WxT[i] = f32_to_bf16(W[k * 1024 + n]);
  } else {
    int v = i - 256 * 1024;        // [0, 65536)
    int p = v >> 9, t = v & 511;
    int j = t >> 1;
    int colA = (t & 1) ? 512 + j : j;
    int colB = (t & 1) ? 768 + j : 256 + j;
    unsigned int aLo = (unsigned int)__builtin_bit_cast(unsigned short, (_Float16)W[(256 + 2 * p) * 1024 + colA]);
    unsigned int aHi = (unsigned int)__builtin_bit_cast(unsigned short, (_Float16)W[(257 + 2 * p) * 1024 + colA]);
    unsigned int bLo = (unsigned int)__builtin_bit_cast(unsigned short, (_Float16)W[(256 + 2 * p) * 1024 + colB]);
    unsigned int bHi = (unsigned int)__builtin_bit_cast(unsigned short, (_Float16)W[(257 + 2 * p) * 1024 + colB]);
    Whp2[v] = uint2{aLo | (aHi << 16), bLo | (bHi << 16)};
  }
}

// ---------------- xproj: gates_x = x @ Wx + b (+1 on f-gate) ----------------
// M=131072, N=1024, K=256. Output layout: G[m][j][gate], gate order (i,g,f,o).
__global__ __launch_bounds__(256) void k_xproj(const unsigned short* __restrict__ A,
                                               const unsigned short* __restrict__ BT,
                                               const float* __restrict__ bias,
                                               __half* __restrict__ G) {
  int bm = blockIdx.x * 64;
  int bn = blockIdx.y * 64;
  int lane = threadIdx.x & 63, wave = threadIdx.x >> 6;
  int wm = (wave & 1) * 32, wn = (wave >> 1) * 32;
  int q = lane >> 4, l16 = lane & 15;

  f32x4 acc[2][2] = {};
  const unsigned short* Ab = A + (size_t)(bm + wm + l16) * 256 + q * 8;
  const unsigned short* Bb = BT + (size_t)(bn + wn + l16) * 256 + q * 8;

#pragma unroll
  for (int kk = 0; kk < 8; ++kk) {
    short8 a0 = *(const short8*)(Ab + kk * 32);
    short8 a1 = *(const short8*)(Ab + 16 * 256 + kk * 32);
    short8 b0 = *(const short8*)(Bb + kk * 32);
    short8 b1 = *(const short8*)(Bb + 16 * 256 + kk * 32);
    acc[0][0] = __builtin_amdgcn_mfma_f32_16x16x32_bf16(a0, b0, acc[0][0], 0, 0, 0);
    acc[0][1] = __builtin_amdgcn_mfma_f32_16x16x32_bf16(a0, b1, acc[0][1], 0, 0, 0);
    acc[1][0] = __builtin_amdgcn_mfma_f32_16x16x32_bf16(a1, b0, acc[1][0], 0, 0, 0);
    acc[1][1] = __builtin_amdgcn_mfma_f32_16x16x32_bf16(a1, b1, acc[1][1], 0, 0, 0);
  }

#pragma unroll
  for (int nt = 0; nt < 2; ++nt) {
    int col = bn + wn + nt * 16 + l16;
    float bv = bias[col] + ((col >= 512 && col < 768) ? 1.0f : 0.0f);
    int gate = col >> 8, jj = col & 255;
#pragma unroll
    for (int mt = 0; mt < 2; ++mt) {
#pragma unroll
      for (int r = 0; r < 4; ++r) {
        int row = bm + wm + mt * 16 + q * 4 + r;
        G[(size_t)row * 1024 + jj * 4 + gate] = __float2half_rn(acc[mt][nt][r] + bv);
      }
    }
  }
}

// ---------------- recurrent scan ----------------
// 32 blocks (1 batch/CU) x 512 threads. Thread t: j=t>>1; even->(i,g), odd->(f,o).
__global__ __launch_bounds__(512, 2) void k_scan(const uint2* __restrict__ Whp2,
                                                 const __half* __restrict__ G,
                                                 float* __restrict__ hfin) {
  __shared__ __align__(16) unsigned short h2[2][256];   // h, double-buffered by parity
  __shared__ __align__(16) uint4 WLq4[LQUADS * 512];    // weight tail [i][tid]

  int tid = threadIdx.x;
  int b = blockIdx.x;
  int j = tid >> 1;
  int odd = tid & 1;

  // stage weight tail: WLq4[i*512+tid] = {wA[114+2i], wB[114+2i], wA[115+2i], wB[115+2i]}
#pragma unroll
  for (int i = 0; i < LQUADS; ++i) {
    int p = RPAIRS + 2 * i;
    uint2 u = Whp2[(size_t)p * 512 + tid];
    uint2 v = Whp2[(size_t)(p + 1) * 512 + tid];
    WLq4[i * 512 + tid] = uint4{u.x, u.y, v.x, v.y};
  }

  // register-resident weights: pairs 0..113 for the 2 owned columns
  unsigned int wA[RPAIRS], wB[RPAIRS];
#pragma unroll
  for (int p = 0; p < RPAIRS; ++p) {
    uint2 w = Whp2[(size_t)p * 512 + tid];
    wA[p] = w.x; wB[p] = w.y;
  }
  if (tid < 256) h2[0][tid] = 0;   // h0 = 0
  float cst = 0.0f;                // live in odd lanes

  const unsigned short* gp = (const unsigned short*)G + (size_t)b * T_STEPS * 1024 + j * 4 + odd * 2;
  unsigned int gx_next = *(const unsigned int*)gp;   // step 0 (i,g) or (f,o)
  __syncthreads();

  for (int step = 0; step < T_STEPS; ++step) {
    unsigned int gx_cur = gx_next;
    if (step + 1 < T_STEPS)
      gx_next = *(const unsigned int*)(gp + (size_t)(step + 1) * 1024);  // in flight across barrier

    const uint4* h2q = (const uint4*)h2[step & 1];

    half2_t gxh = __builtin_bit_cast(half2_t, gx_cur);
    float accA0 = (float)gxh.x, accB0 = (float)gxh.y;
    float accA1 = 0.0f, accB1 = 0.0f;

    // chunks 0..27: pairs 0..111 resident, h via uniform b128 broadcast
#pragma unroll
    for (int ch = 0; ch < 28; ++ch) {
      uint4 hh = h2q[ch];
      accA0 = fdot2f(wA[ch * 4 + 0], hh.x, accA0); accB0 = fdot2f(wB[ch * 4 + 0], hh.x, accB0);
      accA1 = fdot2f(wA[ch * 4 + 1], hh.y, accA1); accB1 = fdot2f(wB[ch * 4 + 1], hh.y, accB1);
      accA0 = fdot2f(wA[ch * 4 + 2], hh.z, accA0); accB0 = fdot2f(wB[ch * 4 + 2], hh.z, accB0);
      accA1 = fdot2f(wA[ch * 4 + 3], hh.w, accA1); accB1 = fdot2f(wB[ch * 4 + 3], hh.w, accB1);
    }
    { // chunk 28: pairs 112,113 (resident) + 114,115 (WLq4[0])
      uint4 hh = h2q[28];
      uint4 q0 = WLq4[0 * 512 + tid];
      accA0 = fdot2f(wA[112], hh.x, accA0); accB0 = fdot2f(wB[112], hh.x, accB0);
      accA1 = fdot2f(wA[113], hh.y, accA1); accB1 = fdot2f(wB[113], hh.y, accB1);
      accA0 = fdot2f(q0.x, hh.z, accA0);    accB0 = fdot2f(q0.y, hh.z, accB0);
      accA1 = fdot2f(q0.z, hh.w, accA1);    accB1 = fdot2f(q0.w, hh.w, accB1);
    }
    // chunks 29..31: pairs 116..127 via WLq4[1..6]
#pragma unroll
    for (int ch = 0; ch < 3; ++ch) {
      uint4 hh = h2q[29 + ch];
      uint4 q0 = WLq4[(1 + 2 * ch) * 512 + tid];
      uint4 q1 = WLq4[(2 + 2 * ch) * 512 + tid];
      accA0 = fdot2f(q0.x, hh.x, accA0); accB0 = fdot2f(q0.y, hh.x, accB0);
      accA1 = fdot2f(q0.z, hh.y, accA1); accB1 = fdot2f(q0.w, hh.y, accB1);
      accA0 = fdot2f(q1.x, hh.z, accA0); accB0 = fdot2f(q1.y, hh.z, accB0);
      accA1 = fdot2f(q1.z, hh.w, accA1); accB1 = fdot2f(q1.w, hh.w, accB1);
    }

    // ---- epilogue, distributed: A = i|f, B = g|o ----
    float Av = accA0 + accA1;   // even: i_j ; odd: f_j (+1 folded)
    float Bv = accB0 + accB1;   // even: g_j ; odd: o_j
    float sA = 1.0f / (1.0f + __expf(-Av));            // si | sf
    float eB = __expf(2.0f * Bv);
    float tB = 1.0f - 2.0f / (eB + 1.0f);              // tanh(g) | tanh(o)-unused
    float a = sA * tB;                                 // even: si*tanh(g)
    float a_x = __shfl_xor(a, 1, 64);                  // odd receives even's a
    if (odd) {
      float so = 1.0f / (1.0f + __expf(-Bv));
      cst = sA * cst + a_x;                            // c = sf*c + si*tanh(g)
      float ec = __expf(2.0f * cst);
      float tc = 1.0f - 2.0f / (ec + 1.0f);
      float h = so * tc;
      h2[(step + 1) & 1][j] = __builtin_bit_cast(unsigned short, (_Float16)h);
      if (step == T_STEPS - 1) hfin[b * 256 + j] = h;
    }

    // ONE raw barrier: drain LDS writes only; G-prefetch (vmcnt) stays in flight
    asm volatile("s_waitcnt lgkmcnt(0)\n\ts_barrier" ::: "memory");
  }
}

// ---------------- head: out = (h@Wfc+bfc)@Wout+bout ----------------
__global__ void k_head(const float* __restrict__ hfin, const float* __restrict__ Wfc,
                       const float* __restrict__ bfc, const float* __restrict__ Wout,
                       const float* __restrict__ bout, float* __restrict__ out) {
  __shared__ float hs[256];
  __shared__ float fcs[256];
  int b = blockIdx.x, j = threadIdx.x;
  hs[j] = hfin[b * 256 + j];
  __syncthreads();
  float acc = bfc[j];
#pragma unroll 8
  for (int k = 0; k < 256; ++k) acc += hs[k] * Wfc[k * 256 + j];
  fcs[j] = acc;
  __syncthreads();
  if (j < 24) {
    float a2 = bout[j];
#pragma unroll 8
    for (int k = 0; k < 256; ++k) a2 += fcs[k] * Wout[k * 24 + j];
    out[b * 24 + j] = a2;
  }
}

extern "C" void kernel_launch(void* const* d_in, const int* in_sizes, int n_in,
                              void* d_out, int out_size, void* d_ws, size_t ws_size,
                              hipStream_t stream) {
  const float* x    = (const float*)d_in[0];
  const float* Wl   = (const float*)d_in[1];
  const float* bl   = (const float*)d_in[2];
  const float* Wfc  = (const float*)d_in[3];
  const float* bfc  = (const float*)d_in[4];
  const float* Wout = (const float*)d_in[5];
  const float* bout = (const float*)d_in[6];
  float* out = (float*)d_out;

  char* ws = (char*)d_ws;
  // ws layout (bytes), total ~321 MB
  unsigned short* xbf = (unsigned short*)ws;                    //  67108864  x as bf16
  unsigned short* WxT = (unsigned short*)(ws + 67108864);       //    524288  Wx^T bf16 [1024][256]
  uint2*          Whp2= (uint2*)(ws + 67633152);                //    524288  Wh pairs [128][512] per-thread
  __half*         G   = (__half*)(ws + 68157440);               // 268435456  gates_x f16 [m][j][gate]
  float*          hfin= (float*)(ws + 336592896);               //     32768  final h f32

  k_prep_x<<<32768, 256, 0, stream>>>((const float4*)x, xbf, 8388608);
  k_prep_w<<<1280, 256, 0, stream>>>(Wl, WxT, Whp2);
  dim3 gx(2048, 16, 1);
  k_xproj<<<gx, 256, 0, stream>>>(xbf, WxT, bl, G);
  k_scan<<<32, 512, 0, stream>>>(Whp2, G, hfin);
  k_head<<<32, 256, 0, stream>>>(hfin, Wfc, bfc, Wout, bout, out);
}